// Round 4
// baseline (1021.002 us; speedup 1.0000x reference)
//
#include <hip/hip_runtime.h>

// ---------------- types / helpers ----------------
typedef float  f32x4  __attribute__((ext_vector_type(4)));
typedef __bf16 bf16x4 __attribute__((ext_vector_type(4)));
typedef __bf16 bf16x8 __attribute__((ext_vector_type(8)));

#define MFMA16(a,b,c) __builtin_amdgcn_mfma_f32_16x16x32_bf16((a),(b),(c),0,0,0)

__device__ __forceinline__ void async_copy16(void* lds, const void* gmem) {
  __builtin_amdgcn_global_load_lds(
      (const __attribute__((address_space(1))) void*)gmem,
      (__attribute__((address_space(3))) void*)lds, 16, 0, 0);
}

template<int N> __device__ __forceinline__ void vmcnt_gate() {
  if constexpr (N == 8) asm volatile("s_waitcnt vmcnt(8)" ::: "memory");
  else if constexpr (N == 6) asm volatile("s_waitcnt vmcnt(6)" ::: "memory");
  else if constexpr (N == 2) asm volatile("s_waitcnt vmcnt(2)" ::: "memory");
  else if constexpr (N == 0) asm volatile("s_waitcnt vmcnt(0)" ::: "memory");
  __builtin_amdgcn_sched_barrier(0);
}

// drain ALL ds_reads issued this phase (m201 idiom); sched_barrier fences MFMA hoist (rule #18)
#define LGKM0 do { asm volatile("s_waitcnt lgkmcnt(0)" ::: "memory"); \
                   __builtin_amdgcn_sched_barrier(0); } while (0)

#define BARRIER do { __builtin_amdgcn_sched_barrier(0); \
                     __builtin_amdgcn_s_barrier(); } while (0)

// ---------------- convert f32 -> bf16 (vectorized x4) ----------------
__global__ __launch_bounds__(256) void convert_kernel(const float* __restrict__ in,
                                                      __bf16* __restrict__ out, size_t n4) {
  size_t i = (size_t)blockIdx.x * 256 + threadIdx.x;
  if (i >= n4) return;
  f32x4 v = *(const f32x4*)(in + i * 4);
  bf16x4 o;
  #pragma unroll
  for (int j = 0; j < 4; ++j) o[j] = (__bf16)v[j];
  *(bf16x4*)(out + i * 4) = o;
}

// ---------------- transpose + convert: in f32 (R,C) -> out bf16 (C,R) ----------------
__global__ __launch_bounds__(256) void transpose_kernel(const float* __restrict__ in,
                                                        __bf16* __restrict__ out, int R, int C) {
  __shared__ float tile[32][33];
  int bx = blockIdx.x, by = blockIdx.y;
  int tx = threadIdx.x & 31, ty0 = threadIdx.x >> 5;
  #pragma unroll
  for (int i = 0; i < 4; ++i) {
    int r = by * 32 + ty0 + i * 8;
    tile[ty0 + i * 8][tx] = in[(size_t)r * C + bx * 32 + tx];
  }
  __syncthreads();
  #pragma unroll
  for (int i = 0; i < 4; ++i) {
    int c = bx * 32 + ty0 + i * 8;
    out[(size_t)c * R + by * 32 + tx] = (__bf16)tile[tx][ty0 + i * 8];
  }
}

// ---------------- 256x256 8-phase bf16 GEMM (m201 phase discipline) ----------------
// C(M,N) = A(M,K) * Bt(N,K)^T. 512 threads = 8 waves (2M x 4N), wave out 128x64.
// LDS 128KB: 2 bufs x {A[256][64], B[256][64]} bf16, XOR-swizzled 16B groups.
// R4 structure (ported from the proven m201 template, 62% MfmaUtil on this HW):
//   block i = { ds_reads for THIS block's MFMA | stages | s_barrier |
//               lgkmcnt(0) | setprio 16xMFMA | [vmcnt gate] | s_barrier }
// Mechanism: waves leave the previous MFMA cluster STAGGERED (matrix pipe serializes
// them); each wave issues its reads on exit and they drain while slower waves finish
// MFMAs; barrier-A re-converges; lgkm(0) is then ~free. Single-set a[4]/b[4] frags
// (b read blocks 0/2, lives 2 blocks; a overwritten per block).
//   block0: read a(h0,k0)+b(k0)[buf]; LATE(tau+1->nbuf A q1,q3); M0 acc[0..3]; G0
//   block1: read a(h1,k0);                                       M1 acc[4..7]
//   block2: read a(h0,k1)+b(k1);                                 M2 acc[0..3]
//   block3: read a(h1,k1); EARLY(tau+2->buf A q0,q2 + B q0..3);  M3 acc[4..7]; G3
// Hazards: stage regions' readers all drained by that block's lgkm(0) + fenced by
// BARRIER_B before the stage issues (LATE targets nbuf h1-rows, last read block3(tau-1);
// EARLY targets buf q0,q2/B, last read block2(tau)). Gates BEFORE their barrier
// (per-wave vmcnt + barrier => cross-wave visibility; R2 lesson):
//   G0=vmcnt(8) end-block0: FIFO [...,LATE(tau)2 | EARLY(tau+1)6, LATE(tau+1)2]
//     -> LATE(tau) landed before block1 reads q1,q3.
//   G3=vmcnt(8) end-block3: FIFO [...,EARLY(tau+1)6 | LATE(tau+1)2, EARLY(tau+2)6]
//     -> EARLY(tau+1) landed before block0(tau+1) reads.
// Tail: tau=T-2 G3=vmcnt(2); tau=T-1 G0=vmcnt(0), no G3.

__device__ __forceinline__ void stage_q(__bf16* region, int qrow, const __bf16* src,
                                        int K, int w, int l) {
  int r = qrow + w * 8 + (l >> 3);
  async_copy16(region + (size_t)(qrow + w * 8) * 64,
               src + (size_t)r * K + (((l & 7) ^ (r & 7)) << 3));
}

template<bool LATE, bool EARLY, int G0, int G3>
__device__ __forceinline__ void tile_body(__bf16* smem,
                                          const __bf16* Apan, const __bf16* Bpan,
                                          int K, int tau, int wm, int wn,
                                          int lo, int hi, int w, int l,
                                          bf16x8 (&a)[4], bf16x8 (&b)[4],
                                          f32x4 (&acc)[8][4]) {
  const int buf = tau & 1;
  __bf16* Ab = smem + buf * 32768;
  __bf16* Bb = Ab + 16384;
  __bf16* An = smem + (buf ^ 1) * 32768;

  // ---- block0: reads a(h0,k0)+b(k0); LATE stages; bar; lgkm0; M0; G0; bar
  #pragma unroll
  for (int t = 0; t < 4; ++t) {
    int ra = wm * 128 + t * 16 + lo;
    a[t] = *(const bf16x8*)(Ab + (size_t)ra * 64 + ((hi ^ (ra & 7)) << 3));
  }
  #pragma unroll
  for (int t = 0; t < 4; ++t) {
    int rb = wn * 64 + t * 16 + lo;
    b[t] = *(const bf16x8*)(Bb + (size_t)rb * 64 + ((hi ^ (rb & 7)) << 3));
  }
  if constexpr (LATE) {
    const __bf16* Ap1 = Apan + (size_t)(tau + 1) * 64;
    stage_q(An, 64,  Ap1, K, w, l);   // A q1
    stage_q(An, 192, Ap1, K, w, l);   // A q3
  }
  BARRIER;
  LGKM0;
  __builtin_amdgcn_s_setprio(1);
  #pragma unroll
  for (int mt = 0; mt < 4; ++mt)
    #pragma unroll
    for (int nt = 0; nt < 4; ++nt)
      acc[mt][nt] = MFMA16(a[mt], b[nt], acc[mt][nt]);
  __builtin_amdgcn_s_setprio(0);
  if constexpr (G0 >= 0) vmcnt_gate<G0>();
  BARRIER;

  // ---- block1: reads a(h1,k0); bar; lgkm0; M1; bar
  #pragma unroll
  for (int t = 0; t < 4; ++t) {
    int ra = wm * 128 + 64 + t * 16 + lo;
    a[t] = *(const bf16x8*)(Ab + (size_t)ra * 64 + ((hi ^ (ra & 7)) << 3));
  }
  BARRIER;
  LGKM0;
  __builtin_amdgcn_s_setprio(1);
  #pragma unroll
  for (int mt = 0; mt < 4; ++mt)
    #pragma unroll
    for (int nt = 0; nt < 4; ++nt)
      acc[4 + mt][nt] = MFMA16(a[mt], b[nt], acc[4 + mt][nt]);
  __builtin_amdgcn_s_setprio(0);
  BARRIER;

  // ---- block2: reads a(h0,k1)+b(k1); bar; lgkm0; M2; bar
  #pragma unroll
  for (int t = 0; t < 4; ++t) {
    int ra = wm * 128 + t * 16 + lo;
    a[t] = *(const bf16x8*)(Ab + (size_t)ra * 64 + (((4 + hi) ^ (ra & 7)) << 3));
  }
  #pragma unroll
  for (int t = 0; t < 4; ++t) {
    int rb = wn * 64 + t * 16 + lo;
    b[t] = *(const bf16x8*)(Bb + (size_t)rb * 64 + (((4 + hi) ^ (rb & 7)) << 3));
  }
  BARRIER;
  LGKM0;
  __builtin_amdgcn_s_setprio(1);
  #pragma unroll
  for (int mt = 0; mt < 4; ++mt)
    #pragma unroll
    for (int nt = 0; nt < 4; ++nt)
      acc[mt][nt] = MFMA16(a[mt], b[nt], acc[mt][nt]);
  __builtin_amdgcn_s_setprio(0);
  BARRIER;

  // ---- block3: reads a(h1,k1); EARLY stages; bar; lgkm0; M3; G3; bar
  #pragma unroll
  for (int t = 0; t < 4; ++t) {
    int ra = wm * 128 + 64 + t * 16 + lo;
    a[t] = *(const bf16x8*)(Ab + (size_t)ra * 64 + (((4 + hi) ^ (ra & 7)) << 3));
  }
  if constexpr (EARLY) {
    const __bf16* Ap2 = Apan + (size_t)(tau + 2) * 64;
    const __bf16* Bp2 = Bpan + (size_t)(tau + 2) * 64;
    stage_q(Ab, 0,   Ap2, K, w, l);   // A q0
    stage_q(Ab, 128, Ap2, K, w, l);   // A q2
    stage_q(Bb, 0,   Bp2, K, w, l);   // B q0
    stage_q(Bb, 64,  Bp2, K, w, l);   // B q1
    stage_q(Bb, 128, Bp2, K, w, l);   // B q2
    stage_q(Bb, 192, Bp2, K, w, l);   // B q3
  }
  BARRIER;
  LGKM0;
  __builtin_amdgcn_s_setprio(1);
  #pragma unroll
  for (int mt = 0; mt < 4; ++mt)
    #pragma unroll
    for (int nt = 0; nt < 4; ++nt)
      acc[4 + mt][nt] = MFMA16(a[mt], b[nt], acc[4 + mt][nt]);
  __builtin_amdgcn_s_setprio(0);
  if constexpr (G3 >= 0) vmcnt_gate<G3>();
  BARRIER;
}

template <typename CT>
__global__ __launch_bounds__(512, 2) void gemm256_kernel(const __bf16* __restrict__ A,
                                                         const __bf16* __restrict__ Bt,
                                                         CT* __restrict__ C, int M, int N, int K) {
  extern __shared__ __bf16 smem[];

  // XCD-bijective block swizzle (all grids have nwg % 8 == 0)
  const int gx = gridDim.x;
  const int nwg = gx * gridDim.y;
  const int wg = blockIdx.y * gx + blockIdx.x;
  const int qq = nwg >> 3;
  const int id2 = (wg & 7) * qq + (wg >> 3);
  const int m0 = (id2 / gx) * 256, n0 = (id2 % gx) * 256;

  const int tid = threadIdx.x;
  const int l = tid & 63, w = tid >> 6;
  const int lo = l & 15, hi = l >> 4;
  const int wm = w >> 2, wn = w & 3;

  const __bf16* Apan = A + (size_t)m0 * K;
  const __bf16* Bpan = Bt + (size_t)n0 * K;

  f32x4 acc[8][4] = {};
  bf16x8 a[4], b[4];

  // prologue: stage tile0 full (8) then tile1 EARLY-set (6); LATE(tile1) comes at
  // block0(0). vmcnt(6) = tile0 landed (per-wave) BEFORE barrier -> visible to all.
  stage_q(smem,          0,   Apan, K, w, l);
  stage_q(smem,          64,  Apan, K, w, l);
  stage_q(smem,          128, Apan, K, w, l);
  stage_q(smem,          192, Apan, K, w, l);
  stage_q(smem + 16384,  0,   Bpan, K, w, l);
  stage_q(smem + 16384,  64,  Bpan, K, w, l);
  stage_q(smem + 16384,  128, Bpan, K, w, l);
  stage_q(smem + 16384,  192, Bpan, K, w, l);
  stage_q(smem + 32768,  0,   Apan + 64, K, w, l);
  stage_q(smem + 32768,  128, Apan + 64, K, w, l);
  stage_q(smem + 49152,  0,   Bpan + 64, K, w, l);
  stage_q(smem + 49152,  64,  Bpan + 64, K, w, l);
  stage_q(smem + 49152,  128, Bpan + 64, K, w, l);
  stage_q(smem + 49152,  192, Bpan + 64, K, w, l);
  vmcnt_gate<6>();
  BARRIER;

  const int T = K >> 6;
  for (int tau = 0; tau < T - 2; ++tau)
    tile_body<true,  true,  8, 8>(smem, Apan, Bpan, K, tau,   wm, wn, lo, hi, w, l, a, b, acc);
  tile_body<true,  false, 8, 2>(smem, Apan, Bpan, K, T - 2, wm, wn, lo, hi, w, l, a, b, acc);
  tile_body<false, false, 0, -1>(smem, Apan, Bpan, K, T - 1, wm, wn, lo, hi, w, l, a, b, acc);

  #pragma unroll
  for (int mt = 0; mt < 8; ++mt)
    #pragma unroll
    for (int nt = 0; nt < 4; ++nt) {
      int col = n0 + wn * 64 + nt * 16 + lo;
      #pragma unroll
      for (int r = 0; r < 4; ++r) {
        int row = m0 + wm * 128 + mt * 16 + 4 * hi + r;
        C[(size_t)row * N + col] = (CT)acc[mt][nt][r];
      }
    }
}

// ---------------- RoPE: in bf16 (b,s,H*256) -> out bf16 (b,H,s,256) ----------------
__global__ __launch_bounds__(256) void rope_kernel(const __bf16* __restrict__ qin,
                                                   const float* __restrict__ cosT,
                                                   const float* __restrict__ sinT,
                                                   __bf16* __restrict__ outp, int H, int bshift) {
  int idx = blockIdx.x * 256 + threadIdx.x;
  int j = idx & 31;
  int s = (idx >> 5) & 4095;
  int h = (idx >> 17) & (H - 1);
  int b = idx >> bshift;
  int d = j * 4;
  size_t ibase = ((size_t)(b * 4096 + s)) * (H * 256) + h * 256 + d;
  bf16x4 x1 = *(const bf16x4*)&qin[ibase];
  bf16x4 x2 = *(const bf16x4*)&qin[ibase + 128];
  f32x4 c  = *(const f32x4*)&cosT[s * 128 + d];
  f32x4 sn = *(const f32x4*)&sinT[s * 128 + d];
  bf16x4 o1, o2;
  #pragma unroll
  for (int t = 0; t < 4; ++t) {
    float a = (float)x1[t], bb = (float)x2[t];
    o1[t] = (__bf16)(a * c[t] - bb * sn[t]);
    o2[t] = (__bf16)(a * sn[t] + bb * c[t]);
  }
  size_t obase = (((size_t)(b * H + h)) * 4096 + s) * 256 + d;
  *(bf16x4*)&outp[obase] = o1;
  *(bf16x4*)&outp[obase + 128] = o2;
}

// ---------------- V permute: (b,s,8*256) bf16 -> (b,8,s,256) bf16 ----------------
__global__ __launch_bounds__(256) void vperm_kernel(const __bf16* __restrict__ in,
                                                    __bf16* __restrict__ out) {
  int idx = blockIdx.x * 256 + threadIdx.x;
  int j = idx & 31;
  int s = (idx >> 5) & 4095;
  int kv = (idx >> 17) & 7;
  int b = idx >> 20;
  bf16x8 v = *(const bf16x8*)&in[((size_t)(b * 4096 + s)) * 2048 + kv * 256 + j * 8];
  *(bf16x8*)&out[(((size_t)(b * 8 + kv)) * 4096 + s) * 256 + j * 8] = v;
}

// ---------------- feature map ----------------
__global__ __launch_bounds__(256) void fm_kernel(const __bf16* __restrict__ rope,
                                                 const float* __restrict__ fm,
                                                 __bf16* __restrict__ out, int srcH, float scale) {
  __shared__ __bf16 fmT[64][256];  // [f][d] swizzled: group' = (d>>3) ^ (f&7)
  int bh = blockIdx.y;
  int h = bh & 15, b = bh >> 4;
  int s0 = blockIdx.x * 128;
  int tid = threadIdx.x, lane = tid & 63, wid = tid >> 6, hi = lane >> 4, lo = lane & 15;

  const float* fmh = fm + (size_t)h * 256 * 64;
  for (int i = tid; i < 256 * 64; i += 256) {
    int d = i >> 6, f = i & 63;
    fmT[f][(((d >> 3) ^ (f & 7)) << 3) | (d & 7)] = (__bf16)fmh[i];
  }
  __syncthreads();

  int srch = (srcH == 16) ? h : (h >> 1);
  const __bf16* abase = rope + ((size_t)(b * srcH + srch) * 4096 + s0 + 32 * wid) * 256;
  f32x4 acc[2][4] = {};
  for (int kk = 0; kk < 256; kk += 32) {
    bf16x8 a[2], bf[4];
    #pragma unroll
    for (int mt = 0; mt < 2; ++mt)
      a[mt] = *(const bf16x8*)(abase + (size_t)(16 * mt + lo) * 256 + kk + 8 * hi);
    const int G = (kk >> 3) + hi;
    #pragma unroll
    for (int nt = 0; nt < 4; ++nt) {
      int f = 16 * nt + lo;
      bf[nt] = *(const bf16x8*)&fmT[f][(G ^ (f & 7)) << 3];
    }
    #pragma unroll
    for (int mt = 0; mt < 2; ++mt)
      #pragma unroll
      for (int nt = 0; nt < 4; ++nt)
        acc[mt][nt] = MFMA16(a[mt], bf[nt], acc[mt][nt]);
  }

  size_t obase = ((size_t)(b * 16 + h) * 4096 + s0 + 32 * wid);
  #pragma unroll
  for (int mt = 0; mt < 2; ++mt) {
    #pragma unroll
    for (int r = 0; r < 4; ++r) {
      float z0 = acc[mt][0][r], z1 = acc[mt][1][r], z2 = acc[mt][2][r], z3 = acc[mt][3][r];
      float mx = fmaxf(fmaxf(z0, z1), fmaxf(z2, z3));
      float mn = fminf(fminf(z0, z1), fminf(z2, z3));
      #pragma unroll
      for (int off = 1; off < 16; off <<= 1) {
        mx = fmaxf(mx, __shfl_xor(mx, off));
        mn = fminf(mn, __shfl_xor(mn, off));
      }
      float ep0 = __expf(z0 - mx), ep1 = __expf(z1 - mx), ep2 = __expf(z2 - mx), ep3 = __expf(z3 - mx);
      float en0 = __expf(mn - z0), en1 = __expf(mn - z1), en2 = __expf(mn - z2), en3 = __expf(mn - z3);
      float sp = ep0 + ep1 + ep2 + ep3, sn = en0 + en1 + en2 + en3;
      #pragma unroll
      for (int off = 1; off < 16; off <<= 1) {
        sp += __shfl_xor(sp, off);
        sn += __shfl_xor(sn, off);
      }
      float rp = scale / sp, rn = scale / sn;
      int row = 16 * mt + 4 * hi + r;
      __bf16* op = out + (obase + row) * 128;
      op[0  + lo] = (__bf16)(ep0 * rp);  op[16 + lo] = (__bf16)(ep1 * rp);
      op[32 + lo] = (__bf16)(ep2 * rp);  op[48 + lo] = (__bf16)(ep3 * rp);
      op[64 + lo] = (__bf16)(en0 * rn);  op[80 + lo] = (__bf16)(en1 * rn);
      op[96 + lo] = (__bf16)(en2 * rn);  op[112 + lo] = (__bf16)(en3 * rn);
    }
  }
}

// ---------------- chunked linear attention ----------------
__global__ __launch_bounds__(256) void attn_kernel(const __bf16* __restrict__ qf,
                                                   const __bf16* __restrict__ kf,
                                                   const __bf16* __restrict__ vp,
                                                   __bf16* __restrict__ o) {
  __shared__ __bf16 k_s[64][128];
  __shared__ __bf16 vT_s[32][64];
  __shared__ __bf16 sc_s[64][64];
  __shared__ __bf16 STb[32][128];

  int bid = blockIdx.x;
  int dvb = bid & 7, h = (bid >> 3) & 15, b = bid >> 7;
  int dv0 = dvb * 32;
  int tid = threadIdx.x, lane = tid & 63, wid = tid >> 6, hi = lane >> 4, lo = lane & 15;

  const __bf16* qh = qf + ((size_t)(b * 16 + h)) * 4096 * 128;
  const __bf16* kh = kf + ((size_t)(b * 16 + h)) * 4096 * 128;
  const __bf16* vh = vp + ((size_t)(b * 8 + (h >> 1))) * 4096 * 256 + dv0;
  __bf16* oh = o + ((size_t)b * 4096) * 4096 + h * 256 + dv0;

  {
    unsigned int* z = (unsigned int*)&STb[0][0];
    for (int i = tid; i < 2048; i += 256) z[i] = 0u;
  }
  f32x4 st[2][2] = {};

  for (int n = 0; n < 64; ++n) {
    int s0 = n * 64;
    #pragma unroll
    for (int i = 0; i < 4; ++i) {
      int rb = (wid * 4 + i) * 4;
      int r = rb + (lane >> 4);
      int Glog = (lane & 15) ^ (r & 7);
      async_copy16(&k_s[rb][0], kh + (size_t)(s0 + r) * 128 + Glog * 8);
    }
    {
      int c = tid >> 2, d8 = (tid & 3) * 8;
      bf16x8 vv = *(const bf16x8*)(vh + (size_t)(s0 + c) * 256 + d8);
      #pragma unroll
      for (int j = 0; j < 8; ++j) {
        int dv = d8 + j;
        vT_s[dv][(((c >> 3) ^ (dv & 7)) << 3) | (c & 7)] = vv[j];
      }
    }
    __syncthreads();

    bf16x8 aq[4];
    #pragma unroll
    for (int kq = 0; kq < 4; ++kq)
      aq[kq] = *(const bf16x8*)(qh + (size_t)(s0 + 16 * wid + lo) * 128 + 32 * kq + 8 * hi);

    f32x4 acc_o[2] = {}, sacc[4] = {};
    #pragma unroll
    for (int nt = 0; nt < 2; ++nt)
      #pragma unroll
      for (int kq = 0; kq < 4; ++kq) {
        int rr = 16 * nt + lo, G = 4 * kq + hi;
        bf16x8 bf = *(const bf16x8*)&STb[rr][(G ^ (rr & 7)) << 3];
        acc_o[nt] = MFMA16(aq[kq], bf, acc_o[nt]);
      }
    #pragma unroll
    for (int nt = 0; nt < 4; ++nt)
      #pragma unroll
      for (int kq = 0; kq < 4; ++kq) {
        int rr = 16 * nt + lo, G = 4 * kq + hi;
        bf16x8 bf = *(const bf16x8*)&k_s[rr][(G ^ (rr & 7)) << 3];
        sacc[nt] = MFMA16(aq[kq], bf, sacc[nt]);
      }
    #pragma unroll
    for (int nt = 0; nt < 4; ++nt)
      #pragma unroll
      for (int r = 0; r < 4; ++r) {
        int c = 16 * wid + 4 * hi + r;
        int cp = 16 * nt + lo;
        float v = (cp <= c) ? sacc[nt][r] : 0.0f;
        sc_s[c][(((cp >> 3) ^ (c & 7)) << 3) | (cp & 7)] = (__bf16)v;
      }
    asm volatile("" ::: "memory");
    #pragma unroll
    for (int nt = 0; nt < 2; ++nt)
      #pragma unroll
      for (int kq = 0; kq < 2; ++kq) {
        int rA = 16 * wid + lo, GA = 4 * kq + hi;
        bf16x8 af = *(const bf16x8*)&sc_s[rA][(GA ^ (rA & 7)) << 3];
        int rB = 16 * nt + lo;
        bf16x8 bf = *(const bf16x8*)&vT_s[rB][(GA ^ (rB & 7)) << 3];
        acc_o[nt] = MFMA16(af, bf, acc_o[nt]);
      }
    #pragma unroll
    for (int nt = 0; nt < 2; ++nt)
      #pragma unroll
      for (int r = 0; r < 4; ++r) {
        int c = 16 * wid + 4 * hi + r;
        oh[(size_t)(s0 + c) * 4096 + 16 * nt + lo] = (__bf16)acc_o[nt][r];
      }
    __syncthreads();

    bf16x8 bu[2][2];
    #pragma unroll
    for (int q = 0; q < 2; ++q) {
      int dk = 16 * (2 * wid + q) + lo;
      #pragma unroll
      for (int kq = 0; kq < 2; ++kq) {
        bf16x8 tmp;
        #pragma unroll
        for (int j = 0; j < 8; ++j) {
          int c = 32 * kq + 8 * hi + j;
          tmp[j] = k_s[c][(((dk >> 3) ^ (c & 7)) << 3) | (dk & 7)];
        }
        bu[q][kq] = tmp;
      }
    }
    #pragma unroll
    for (int mt = 0; mt < 2; ++mt)
      #pragma unroll
      for (int kq = 0; kq < 2; ++kq) {
        int rA = 16 * mt + lo, GA = 4 * kq + hi;
        bf16x8 av = *(const bf16x8*)&vT_s[rA][(GA ^ (rA & 7)) << 3];
        #pragma unroll
        for (int q = 0; q < 2; ++q)
          st[mt][q] = MFMA16(av, bu[q][kq], st[mt][q]);
      }
    #pragma unroll
    for (int mt = 0; mt < 2; ++mt)
      #pragma unroll
      for (int q = 0; q < 2; ++q) {
        int dk = 16 * (2 * wid + q) + lo;
        #pragma unroll
        for (int r = 0; r < 4; ++r) {
          int dvr = 16 * mt + 4 * hi + r;
          STb[dvr][(((dk >> 3) ^ (dvr & 7)) << 3) | (dk & 7)] = (__bf16)st[mt][q][r];
        }
      }
    __syncthreads();
  }
}

// ---------------- launch ----------------
extern "C" void kernel_launch(void* const* d_in, const int* in_sizes, int n_in,
                              void* d_out, int out_size, void* d_ws, size_t ws_size,
                              hipStream_t stream) {
  (void)in_sizes; (void)n_in; (void)out_size; (void)ws_size;
  const float* hs   = (const float*)d_in[0];
  const float* cosT = (const float*)d_in[1];
  const float* sinT = (const float*)d_in[2];
  const float* Wq   = (const float*)d_in[3];
  const float* Wk   = (const float*)d_in[4];
  const float* Wv   = (const float*)d_in[5];
  const float* Wo   = (const float*)d_in[6];
  const float* fmq  = (const float*)d_in[7];
  const float* fmk  = (const float*)d_in[8];
  float* out = (float*)d_out;
  char* ws = (char*)d_ws;

  hipFuncSetAttribute((const void*)gemm256_kernel<__bf16>,
                      hipFuncAttributeMaxDynamicSharedMemorySize, 131072);
  hipFuncSetAttribute((const void*)gemm256_kernel<float>,
                      hipFuncAttributeMaxDynamicSharedMemorySize, 131072);

  const size_t MB = 1024ull * 1024ull;
  __bf16* Xb   = (__bf16*)(ws + 0);
  __bf16* ropq = (__bf16*)(ws + 0);
  __bf16* Wqt  = (__bf16*)(ws + 70 * MB);
  __bf16* ropk = (__bf16*)(ws + 70 * MB);
  __bf16* Wkt  = (__bf16*)(ws + 104 * MB);
  __bf16* vpb  = (__bf16*)(ws + 104 * MB);
  __bf16* Wvt  = (__bf16*)(ws + 119 * MB);
  __bf16* Wot  = (__bf16*)(ws + 140 * MB);
  __bf16* Qb   = (__bf16*)(ws + 170 * MB);
  __bf16* ob   = (__bf16*)(ws + 170 * MB);
  __bf16* Kb   = (__bf16*)(ws + 238 * MB);
  __bf16* qfb  = (__bf16*)(ws + 238 * MB);
  __bf16* Vb   = (__bf16*)(ws + 272 * MB);
  __bf16* kfb  = (__bf16*)(ws + 272 * MB);

  convert_kernel<<<28672, 256, 0, stream>>>(hs, Xb, (size_t)8192 * 3584 / 4);
  transpose_kernel<<<dim3(128, 112), 256, 0, stream>>>(Wq, Wqt, 3584, 4096);
  transpose_kernel<<<dim3(64, 112),  256, 0, stream>>>(Wk, Wkt, 3584, 2048);
  transpose_kernel<<<dim3(64, 112),  256, 0, stream>>>(Wv, Wvt, 3584, 2048);
  transpose_kernel<<<dim3(112, 128), 256, 0, stream>>>(Wo, Wot, 4096, 3584);

  gemm256_kernel<__bf16><<<dim3(16, 32), 512, 131072, stream>>>(Xb, Wqt, Qb, 8192, 4096, 3584);
  gemm256_kernel<__bf16><<<dim3(8, 32),  512, 131072, stream>>>(Xb, Wkt, Kb, 8192, 2048, 3584);
  gemm256_kernel<__bf16><<<dim3(8, 32),  512, 131072, stream>>>(Xb, Wvt, Vb, 8192, 2048, 3584);

  rope_kernel<<<16384, 256, 0, stream>>>(Qb, cosT, sinT, ropq, 16, 21);
  rope_kernel<<<8192, 256, 0, stream>>>(Kb, cosT, sinT, ropk, 8, 20);
  vperm_kernel<<<8192, 256, 0, stream>>>(Vb, vpb);

  fm_kernel<<<dim3(32, 32), 256, 0, stream>>>(ropq, fmq, qfb, 16, 0.08838834764831845f);
  fm_kernel<<<dim3(32, 32), 256, 0, stream>>>(ropk, fmk, kfb, 8, 1.0f);

  attn_kernel<<<256, 256, 0, stream>>>(qfb, kfb, vpb, ob);

  gemm256_kernel<float><<<dim3(14, 32), 512, 131072, stream>>>(ob, Wot, out, 8192, 3584, 4096);
}

// Round 5
// 957.712 us; speedup vs baseline: 1.0661x; 1.0661x over previous
//
#include <hip/hip_runtime.h>

// ---------------- types / helpers ----------------
typedef float  f32x4  __attribute__((ext_vector_type(4)));
typedef __bf16 bf16x4 __attribute__((ext_vector_type(4)));
typedef __bf16 bf16x8 __attribute__((ext_vector_type(8)));

#define MFMA16(a,b,c) __builtin_amdgcn_mfma_f32_16x16x32_bf16((a),(b),(c),0,0,0)

__device__ __forceinline__ void async_copy16(void* lds, const void* gmem) {
  __builtin_amdgcn_global_load_lds(
      (const __attribute__((address_space(1))) void*)gmem,
      (__attribute__((address_space(3))) void*)lds, 16, 0, 0);
}

template<int N> __device__ __forceinline__ void vmcnt_gate() {
  if constexpr (N == 8) asm volatile("s_waitcnt vmcnt(8)" ::: "memory");
  else if constexpr (N == 6) asm volatile("s_waitcnt vmcnt(6)" ::: "memory");
  else if constexpr (N == 4) asm volatile("s_waitcnt vmcnt(4)" ::: "memory");
  else if constexpr (N == 2) asm volatile("s_waitcnt vmcnt(2)" ::: "memory");
  else if constexpr (N == 0) asm volatile("s_waitcnt vmcnt(0)" ::: "memory");
  __builtin_amdgcn_sched_barrier(0);
}

// counted lgkm wait: drains all ds_reads OLDER than the N just issued (rule #18 fences)
#define LGKM(N) do { __builtin_amdgcn_sched_barrier(0); \
                     asm volatile("s_waitcnt lgkmcnt(" #N ")" ::: "memory"); \
                     __builtin_amdgcn_sched_barrier(0); } while (0)

#define BARRIER do { __builtin_amdgcn_sched_barrier(0); \
                     __builtin_amdgcn_s_barrier(); \
                     __builtin_amdgcn_sched_barrier(0); } while (0)

// ---------------- convert f32 -> bf16 (vectorized x4) ----------------
__global__ __launch_bounds__(256) void convert_kernel(const float* __restrict__ in,
                                                      __bf16* __restrict__ out, size_t n4) {
  size_t i = (size_t)blockIdx.x * 256 + threadIdx.x;
  if (i >= n4) return;
  f32x4 v = *(const f32x4*)(in + i * 4);
  bf16x4 o;
  #pragma unroll
  for (int j = 0; j < 4; ++j) o[j] = (__bf16)v[j];
  *(bf16x4*)(out + i * 4) = o;
}

// ---------------- transpose + convert: in f32 (R,C) -> out bf16 (C,R) ----------------
__global__ __launch_bounds__(256) void transpose_kernel(const float* __restrict__ in,
                                                        __bf16* __restrict__ out, int R, int C) {
  __shared__ float tile[32][33];
  int bx = blockIdx.x, by = blockIdx.y;
  int tx = threadIdx.x & 31, ty0 = threadIdx.x >> 5;
  #pragma unroll
  for (int i = 0; i < 4; ++i) {
    int r = by * 32 + ty0 + i * 8;
    tile[ty0 + i * 8][tx] = in[(size_t)r * C + bx * 32 + tx];
  }
  __syncthreads();
  #pragma unroll
  for (int i = 0; i < 4; ++i) {
    int c = bx * 32 + ty0 + i * 8;
    out[(size_t)c * R + by * 32 + tx] = (__bf16)tile[tx][ty0 + i * 8];
  }
}

// ---------------- 256x256 pipelined bf16 GEMM (R3 schedule, best measured) ------------
// C(M,N) = A(M,K) * Bt(N,K)^T. 512 threads = 8 waves (2M x 4N), wave out 128x64.
// LDS 128KB: 2 bufs x {A[256][64], B[256][64]} bf16, XOR-swizzled 16B groups.
// K-loop identical to round-3 (978us, MfmaUtil 44.5) — NOT touched this round.
//
// NEW: MODE-fused epilogues (delete rope_q/rope_k/vperm kernels):
//  MODE 0 (O-GEMM): plain row-major C (CT=float).
//  MODE 2 (V-GEMM): n-block == one KV head -> store directly to (b, kv, s, d).
//  MODE 1 (Q/K-GEMM): RoPE fused. B-panel LDS rows are PERMUTED at staging:
//      colmap(s) = ((s>>5)<<4) | (s&15) | (((s>>4)&1)<<7)
//    so wave fragments pair (nt even, nt odd) = global cols (d, d+128) at the SAME
//    lane -> RoPE butterfly is intra-thread on f32 acc (no LDS exchange, single
//    bf16 rounding). acc[mt][nt] column = (2*wn + (nt>>1))*16 + lo + (nt&1)*128.
//    Epilogue stores to rope layout (b, h, s, d) directly.
//  global_load_lds remap: source row = colmap(dest LDS row); dest stays linear;
//  swizzle keyed on dest row (unchanged). Wave still reads 8 consecutive global
//  rows per quantum (no 16-boundary crossing) -> coalescing preserved.

template<bool REMAP>
__device__ __forceinline__ void stage_q(__bf16* region, int qrow, const __bf16* src,
                                        int K, int w, int l) {
  int s = qrow + w * 8 + (l >> 3);
  int gr = REMAP ? (((s >> 5) << 4) | (s & 15) | (((s >> 4) & 1) << 7)) : s;
  async_copy16(region + (size_t)(qrow + w * 8) * 64,
               src + (size_t)gr * K + (((l & 7) ^ (s & 7)) << 3));
}

template<bool LATE, bool EARLY, bool NEXT, int G2, int G3, bool BMAP>
__device__ __forceinline__ void tile_body(__bf16* smem,
                                          const __bf16* Apan, const __bf16* Bpan,
                                          int K, int tau, int wm, int wn,
                                          int lo, int hi, int w, int l,
                                          bf16x8 (&aA)[4], bf16x8 (&aB)[4],
                                          bf16x8 (&bA)[4], bf16x8 (&bB)[4],
                                          f32x4 (&acc)[8][4]) {
  const int buf = tau & 1;
  __bf16* Ab = smem + buf * 32768;
  __bf16* Bb = Ab + 16384;
  __bf16* An = smem + (buf ^ 1) * 32768;
  __bf16* Bn = An + 16384;

  // ---- block0: R1 = aB <- a(h1,k0)[buf]; S0 = LATE; lgkm(4) drains R0; M0 = aA*bA
  #pragma unroll
  for (int t = 0; t < 4; ++t) {
    int ra = wm * 128 + 64 + t * 16 + lo;
    aB[t] = *(const bf16x8*)(Ab + (size_t)ra * 64 + ((hi ^ (ra & 7)) << 3));
  }
  if constexpr (LATE) {
    const __bf16* Ap1 = Apan + (size_t)(tau + 1) * 64;
    stage_q<false>(An, 64,  Ap1, K, w, l);   // A q1
    stage_q<false>(An, 192, Ap1, K, w, l);   // A q3
  }
  LGKM(4);
  __builtin_amdgcn_s_setprio(1);
  #pragma unroll
  for (int mt = 0; mt < 4; ++mt)
    #pragma unroll
    for (int nt = 0; nt < 4; ++nt)
      acc[mt][nt] = MFMA16(aA[mt], bA[nt], acc[mt][nt]);
  __builtin_amdgcn_s_setprio(0);
  BARRIER;

  // ---- block1: R2 = aA <- a(h0,k1), bB <- b(k1) [buf]; lgkm(8) drains R1; M1 = aB*bA
  #pragma unroll
  for (int t = 0; t < 4; ++t) {
    int ra = wm * 128 + t * 16 + lo;
    aA[t] = *(const bf16x8*)(Ab + (size_t)ra * 64 + (((4 + hi) ^ (ra & 7)) << 3));
  }
  #pragma unroll
  for (int t = 0; t < 4; ++t) {
    int rb = wn * 64 + t * 16 + lo;
    bB[t] = *(const bf16x8*)(Bb + (size_t)rb * 64 + (((4 + hi) ^ (rb & 7)) << 3));
  }
  LGKM(8);
  __builtin_amdgcn_s_setprio(1);
  #pragma unroll
  for (int mt = 0; mt < 4; ++mt)
    #pragma unroll
    for (int nt = 0; nt < 4; ++nt)
      acc[4 + mt][nt] = MFMA16(aB[mt], bA[nt], acc[4 + mt][nt]);
  __builtin_amdgcn_s_setprio(0);
  BARRIER;

  // ---- block2: R3 = aB <- a(h1,k1)[buf]; lgkm(4) drains R2; M2 = aA*bB;
  //      G2 gate BEFORE bar2 (cross-wave: EARLY(tau+1) landed for everyone)
  #pragma unroll
  for (int t = 0; t < 4; ++t) {
    int ra = wm * 128 + 64 + t * 16 + lo;
    aB[t] = *(const bf16x8*)(Ab + (size_t)ra * 64 + (((4 + hi) ^ (ra & 7)) << 3));
  }
  LGKM(4);
  __builtin_amdgcn_s_setprio(1);
  #pragma unroll
  for (int mt = 0; mt < 4; ++mt)
    #pragma unroll
    for (int nt = 0; nt < 4; ++nt)
      acc[mt][nt] = MFMA16(aA[mt], bB[nt], acc[mt][nt]);
  __builtin_amdgcn_s_setprio(0);
  if constexpr (G2 >= 0) vmcnt_gate<G2>();
  BARRIER;

  // ---- block3: R0' = aA <- a(h0,k0), bA <- b(k0) [nbuf] (NEXT); S3 = EARLY(tau+2 -> buf);
  //      lgkm(8|0) drains R3; M3 = aB*bB; G3 gate BEFORE bar3 (LATE landed for everyone)
  if constexpr (NEXT) {
    #pragma unroll
    for (int t = 0; t < 4; ++t) {
      int ra = wm * 128 + t * 16 + lo;
      aA[t] = *(const bf16x8*)(An + (size_t)ra * 64 + ((hi ^ (ra & 7)) << 3));
    }
    #pragma unroll
    for (int t = 0; t < 4; ++t) {
      int rb = wn * 64 + t * 16 + lo;
      bA[t] = *(const bf16x8*)(Bn + (size_t)rb * 64 + ((hi ^ (rb & 7)) << 3));
    }
  }
  if constexpr (EARLY) {
    const __bf16* Ap2 = Apan + (size_t)(tau + 2) * 64;
    const __bf16* Bp2 = Bpan + (size_t)(tau + 2) * 64;
    stage_q<false>(Ab, 0,   Ap2, K, w, l);   // A q0
    stage_q<false>(Ab, 128, Ap2, K, w, l);   // A q2
    stage_q<BMAP>(Bb, 0,   Bp2, K, w, l);    // B q0
    stage_q<BMAP>(Bb, 64,  Bp2, K, w, l);    // B q1
    stage_q<BMAP>(Bb, 128, Bp2, K, w, l);    // B q2
    stage_q<BMAP>(Bb, 192, Bp2, K, w, l);    // B q3
  }
  if constexpr (NEXT) LGKM(8); else LGKM(0);
  __builtin_amdgcn_s_setprio(1);
  #pragma unroll
  for (int mt = 0; mt < 4; ++mt)
    #pragma unroll
    for (int nt = 0; nt < 4; ++nt)
      acc[4 + mt][nt] = MFMA16(aB[mt], bB[nt], acc[4 + mt][nt]);
  __builtin_amdgcn_s_setprio(0);
  if constexpr (G3 >= 0) vmcnt_gate<G3>();
  BARRIER;
}

template <typename CT, int MODE>
__global__ __launch_bounds__(512, 2) void gemm256_kernel(const __bf16* __restrict__ A,
                                                         const __bf16* __restrict__ Bt,
                                                         CT* __restrict__ C, int M, int N, int K,
                                                         const float* __restrict__ cosT,
                                                         const float* __restrict__ sinT,
                                                         int Hh) {
  extern __shared__ __bf16 smem[];
  constexpr bool BMAP = (MODE == 1);

  // XCD-bijective block swizzle (all grids have nwg % 8 == 0)
  const int gx = gridDim.x;
  const int nwg = gx * gridDim.y;
  const int wg = blockIdx.y * gx + blockIdx.x;
  const int qq = nwg >> 3;
  const int id2 = (wg & 7) * qq + (wg >> 3);
  const int m0 = (id2 / gx) * 256, n0 = (id2 % gx) * 256;

  const int tid = threadIdx.x;
  const int l = tid & 63, w = tid >> 6;
  const int lo = l & 15, hi = l >> 4;
  const int wm = w >> 2, wn = w & 3;

  const __bf16* Apan = A + (size_t)m0 * K;
  const __bf16* Bpan = Bt + (size_t)n0 * K;

  f32x4 acc[8][4] = {};
  bf16x8 aA[4], aB[4], bA[4], bB[4];

  // prologue: stage tile0 (8 quanta) + tile1 (EARLY order first, LATE last);
  // vmcnt(8) = tile0 landed (per-wave) BEFORE barrier -> cross-wave visible after.
  stage_q<false>(smem,          0,   Apan, K, w, l);
  stage_q<false>(smem,          128, Apan, K, w, l);
  stage_q<BMAP>(smem + 16384,  0,   Bpan, K, w, l);
  stage_q<BMAP>(smem + 16384,  64,  Bpan, K, w, l);
  stage_q<BMAP>(smem + 16384,  128, Bpan, K, w, l);
  stage_q<BMAP>(smem + 16384,  192, Bpan, K, w, l);
  stage_q<false>(smem,          64,  Apan, K, w, l);
  stage_q<false>(smem,          192, Apan, K, w, l);
  stage_q<false>(smem + 32768,  0,   Apan + 64, K, w, l);
  stage_q<false>(smem + 32768,  128, Apan + 64, K, w, l);
  stage_q<BMAP>(smem + 49152,  0,   Bpan + 64, K, w, l);
  stage_q<BMAP>(smem + 49152,  64,  Bpan + 64, K, w, l);
  stage_q<BMAP>(smem + 49152,  128, Bpan + 64, K, w, l);
  stage_q<BMAP>(smem + 49152,  192, Bpan + 64, K, w, l);
  stage_q<false>(smem + 32768,  64,  Apan + 64, K, w, l);
  stage_q<false>(smem + 32768,  192, Apan + 64, K, w, l);
  vmcnt_gate<8>();
  BARRIER;

  #pragma unroll
  for (int t = 0; t < 4; ++t) {
    int ra = wm * 128 + t * 16 + lo;
    aA[t] = *(const bf16x8*)(smem + (size_t)ra * 64 + ((hi ^ (ra & 7)) << 3));
  }
  #pragma unroll
  for (int t = 0; t < 4; ++t) {
    int rb = wn * 64 + t * 16 + lo;
    bA[t] = *(const bf16x8*)(smem + 16384 + (size_t)rb * 64 + ((hi ^ (rb & 7)) << 3));
  }

  const int T = K >> 6;
  tile_body<false, true,  true,  2,  6, BMAP>(smem, Apan, Bpan, K, 0,     wm, wn, lo, hi, w, l, aA, aB, bA, bB, acc);
  for (int tau = 1; tau < T - 2; ++tau)
    tile_body<true, true,  true,  2,  6, BMAP>(smem, Apan, Bpan, K, tau,   wm, wn, lo, hi, w, l, aA, aB, bA, bB, acc);
  tile_body<true,  false, true,  2,  0, BMAP>(smem, Apan, Bpan, K, T - 2, wm, wn, lo, hi, w, l, aA, aB, bA, bB, acc);
  tile_body<false, false, false, -1, -1, BMAP>(smem, Apan, Bpan, K, T - 1, wm, wn, lo, hi, w, l, aA, aB, bA, bB, acc);

  if constexpr (MODE == 0) {
    // plain row-major C
    #pragma unroll
    for (int mt = 0; mt < 8; ++mt)
      #pragma unroll
      for (int nt = 0; nt < 4; ++nt) {
        int col = n0 + wn * 64 + nt * 16 + lo;
        #pragma unroll
        for (int r = 0; r < 4; ++r) {
          int row = m0 + wm * 128 + mt * 16 + 4 * hi + r;
          C[(size_t)row * N + col] = (CT)acc[mt][nt][r];
        }
      }
  } else if constexpr (MODE == 2) {
    // V: store to (b, kv, s, d); n-block == one KV head
    const int kv = n0 >> 8;
    #pragma unroll
    for (int mt = 0; mt < 8; ++mt)
      #pragma unroll
      for (int nt = 0; nt < 4; ++nt) {
        int col = wn * 64 + nt * 16 + lo;
        #pragma unroll
        for (int r = 0; r < 4; ++r) {
          int row = m0 + wm * 128 + mt * 16 + 4 * hi + r;
          int bb = row >> 12, sdx = row & 4095;
          C[(((size_t)(bb * Hh + kv)) * 4096 + sdx) * 256 + col] = (CT)acc[mt][nt][r];
        }
      }
  } else {
    // MODE 1: fused RoPE + store to (b, h, s, d). acc cols are colmap-permuted:
    // pair (nt, nt+1) = (d, d+128) with d = (2*wn + (nt>>1))*16 + lo.
    const int hq = n0 >> 8;
    #pragma unroll
    for (int mt = 0; mt < 8; ++mt)
      #pragma unroll
      for (int ntp = 0; ntp < 4; ntp += 2) {
        int d = (2 * wn + (ntp >> 1)) * 16 + lo;
        #pragma unroll
        for (int r = 0; r < 4; ++r) {
          int row = m0 + wm * 128 + mt * 16 + 4 * hi + r;
          int bb = row >> 12, sdx = row & 4095;
          float cc = cosT[(size_t)sdx * 128 + d];
          float ss = sinT[(size_t)sdx * 128 + d];
          float x1 = acc[mt][ntp][r], x2 = acc[mt][ntp + 1][r];
          size_t base = (((size_t)(bb * Hh + hq)) * 4096 + sdx) * 256;
          C[base + d]       = (CT)(x1 * cc - x2 * ss);
          C[base + d + 128] = (CT)(x1 * ss + x2 * cc);
        }
      }
  }
}

// ---------------- feature map ----------------
__global__ __launch_bounds__(256) void fm_kernel(const __bf16* __restrict__ rope,
                                                 const float* __restrict__ fm,
                                                 __bf16* __restrict__ out, int srcH, float scale) {
  __shared__ __bf16 fmT[64][256];  // [f][d] swizzled: group' = (d>>3) ^ (f&7)
  int bh = blockIdx.y;
  int h = bh & 15, b = bh >> 4;
  int s0 = blockIdx.x * 128;
  int tid = threadIdx.x, lane = tid & 63, wid = tid >> 6, hi = lane >> 4, lo = lane & 15;

  const float* fmh = fm + (size_t)h * 256 * 64;
  for (int i = tid; i < 256 * 64; i += 256) {
    int d = i >> 6, f = i & 63;
    fmT[f][(((d >> 3) ^ (f & 7)) << 3) | (d & 7)] = (__bf16)fmh[i];
  }
  __syncthreads();

  int srch = (srcH == 16) ? h : (h >> 1);
  const __bf16* abase = rope + ((size_t)(b * srcH + srch) * 4096 + s0 + 32 * wid) * 256;
  f32x4 acc[2][4] = {};
  for (int kk = 0; kk < 256; kk += 32) {
    bf16x8 a[2], bf[4];
    #pragma unroll
    for (int mt = 0; mt < 2; ++mt)
      a[mt] = *(const bf16x8*)(abase + (size_t)(16 * mt + lo) * 256 + kk + 8 * hi);
    const int G = (kk >> 3) + hi;
    #pragma unroll
    for (int nt = 0; nt < 4; ++nt) {
      int f = 16 * nt + lo;
      bf[nt] = *(const bf16x8*)&fmT[f][(G ^ (f & 7)) << 3];
    }
    #pragma unroll
    for (int mt = 0; mt < 2; ++mt)
      #pragma unroll
      for (int nt = 0; nt < 4; ++nt)
        acc[mt][nt] = MFMA16(a[mt], bf[nt], acc[mt][nt]);
  }

  size_t obase = ((size_t)(b * 16 + h) * 4096 + s0 + 32 * wid);
  #pragma unroll
  for (int mt = 0; mt < 2; ++mt) {
    #pragma unroll
    for (int r = 0; r < 4; ++r) {
      float z0 = acc[mt][0][r], z1 = acc[mt][1][r], z2 = acc[mt][2][r], z3 = acc[mt][3][r];
      float mx = fmaxf(fmaxf(z0, z1), fmaxf(z2, z3));
      float mn = fminf(fminf(z0, z1), fminf(z2, z3));
      #pragma unroll
      for (int off = 1; off < 16; off <<= 1) {
        mx = fmaxf(mx, __shfl_xor(mx, off));
        mn = fminf(mn, __shfl_xor(mn, off));
      }
      float ep0 = __expf(z0 - mx), ep1 = __expf(z1 - mx), ep2 = __expf(z2 - mx), ep3 = __expf(z3 - mx);
      float en0 = __expf(mn - z0), en1 = __expf(mn - z1), en2 = __expf(mn - z2), en3 = __expf(mn - z3);
      float sp = ep0 + ep1 + ep2 + ep3, sn = en0 + en1 + en2 + en3;
      #pragma unroll
      for (int off = 1; off < 16; off <<= 1) {
        sp += __shfl_xor(sp, off);
        sn += __shfl_xor(sn, off);
      }
      float rp = scale / sp, rn = scale / sn;
      int row = 16 * mt + 4 * hi + r;
      __bf16* op = out + (obase + row) * 128;
      op[0  + lo] = (__bf16)(ep0 * rp);  op[16 + lo] = (__bf16)(ep1 * rp);
      op[32 + lo] = (__bf16)(ep2 * rp);  op[48 + lo] = (__bf16)(ep3 * rp);
      op[64 + lo] = (__bf16)(en0 * rn);  op[80 + lo] = (__bf16)(en1 * rn);
      op[96 + lo] = (__bf16)(en2 * rn);  op[112 + lo] = (__bf16)(en3 * rn);
    }
  }
}

// ---------------- chunked linear attention ----------------
__global__ __launch_bounds__(256) void attn_kernel(const __bf16* __restrict__ qf,
                                                   const __bf16* __restrict__ kf,
                                                   const __bf16* __restrict__ vp,
                                                   __bf16* __restrict__ o) {
  __shared__ __bf16 k_s[64][128];
  __shared__ __bf16 vT_s[32][64];
  __shared__ __bf16 sc_s[64][64];
  __shared__ __bf16 STb[32][128];

  int bid = blockIdx.x;
  int dvb = bid & 7, h = (bid >> 3) & 15, b = bid >> 7;
  int dv0 = dvb * 32;
  int tid = threadIdx.x, lane = tid & 63, wid = tid >> 6, hi = lane >> 4, lo = lane & 15;

  const __bf16* qh = qf + ((size_t)(b * 16 + h)) * 4096 * 128;
  const __bf16* kh = kf + ((size_t)(b * 16 + h)) * 4096 * 128;
  const __bf16* vh = vp + ((size_t)(b * 8 + (h >> 1))) * 4096 * 256 + dv0;
  __bf16* oh = o + ((size_t)b * 4096) * 4096 + h * 256 + dv0;

  {
    unsigned int* z = (unsigned int*)&STb[0][0];
    for (int i = tid; i < 2048; i += 256) z[i] = 0u;
  }
  f32x4 st[2][2] = {};

  for (int n = 0; n < 64; ++n) {
    int s0 = n * 64;
    #pragma unroll
    for (int i = 0; i < 4; ++i) {
      int rb = (wid * 4 + i) * 4;
      int r = rb + (lane >> 4);
      int Glog = (lane & 15) ^ (r & 7);
      async_copy16(&k_s[rb][0], kh + (size_t)(s0 + r) * 128 + Glog * 8);
    }
    {
      int c = tid >> 2, d8 = (tid & 3) * 8;
      bf16x8 vv = *(const bf16x8*)(vh + (size_t)(s0 + c) * 256 + d8);
      #pragma unroll
      for (int j = 0; j < 8; ++j) {
        int dv = d8 + j;
        vT_s[dv][(((c >> 3) ^ (dv & 7)) << 3) | (c & 7)] = vv[j];
      }
    }
    __syncthreads();

    bf16x8 aq[4];
    #pragma unroll
    for (int kq = 0; kq < 4; ++kq)
      aq[kq] = *(const bf16x8*)(qh + (size_t)(s0 + 16 * wid + lo) * 128 + 32 * kq + 8 * hi);

    f32x4 acc_o[2] = {}, sacc[4] = {};
    #pragma unroll
    for (int nt = 0; nt < 2; ++nt)
      #pragma unroll
      for (int kq = 0; kq < 4; ++kq) {
        int rr = 16 * nt + lo, G = 4 * kq + hi;
        bf16x8 bf = *(const bf16x8*)&STb[rr][(G ^ (rr & 7)) << 3];
        acc_o[nt] = MFMA16(aq[kq], bf, acc_o[nt]);
      }
    #pragma unroll
    for (int nt = 0; nt < 4; ++nt)
      #pragma unroll
      for (int kq = 0; kq < 4; ++kq) {
        int rr = 16 * nt + lo, G = 4 * kq + hi;
        bf16x8 bf = *(const bf16x8*)&k_s[rr][(G ^ (rr & 7)) << 3];
        sacc[nt] = MFMA16(aq[kq], bf, sacc[nt]);
      }
    #pragma unroll
    for (int nt = 0; nt < 4; ++nt)
      #pragma unroll
      for (int r = 0; r < 4; ++r) {
        int c = 16 * wid + 4 * hi + r;
        int cp = 16 * nt + lo;
        float v = (cp <= c) ? sacc[nt][r] : 0.0f;
        sc_s[c][(((cp >> 3) ^ (c & 7)) << 3) | (cp & 7)] = (__bf16)v;
      }
    asm volatile("" ::: "memory");
    #pragma unroll
    for (int nt = 0; nt < 2; ++nt)
      #pragma unroll
      for (int kq = 0; kq < 2; ++kq) {
        int rA = 16 * wid + lo, GA = 4 * kq + hi;
        bf16x8 af = *(const bf16x8*)&sc_s[rA][(GA ^ (rA & 7)) << 3];
        int rB = 16 * nt + lo;
        bf16x8 bf = *(const bf16x8*)&vT_s[rB][(GA ^ (rB & 7)) << 3];
        acc_o[nt] = MFMA16(af, bf, acc_o[nt]);
      }
    #pragma unroll
    for (int nt = 0; nt < 2; ++nt)
      #pragma unroll
      for (int r = 0; r < 4; ++r) {
        int c = 16 * wid + 4 * hi + r;
        oh[(size_t)(s0 + c) * 4096 + 16 * nt + lo] = (__bf16)acc_o[nt][r];
      }
    __syncthreads();

    bf16x8 bu[2][2];
    #pragma unroll
    for (int q = 0; q < 2; ++q) {
      int dk = 16 * (2 * wid + q) + lo;
      #pragma unroll
      for (int kq = 0; kq < 2; ++kq) {
        bf16x8 tmp;
        #pragma unroll
        for (int j = 0; j < 8; ++j) {
          int c = 32 * kq + 8 * hi + j;
          tmp[j] = k_s[c][(((dk >> 3) ^ (c & 7)) << 3) | (dk & 7)];
        }
        bu[q][kq] = tmp;
      }
    }
    #pragma unroll
    for (int mt = 0; mt < 2; ++mt)
      #pragma unroll
      for (int kq = 0; kq < 2; ++kq) {
        int rA = 16 * mt + lo, GA = 4 * kq + hi;
        bf16x8 av = *(const bf16x8*)&vT_s[rA][(GA ^ (rA & 7)) << 3];
        #pragma unroll
        for (int q = 0; q < 2; ++q)
          st[mt][q] = MFMA16(av, bu[q][kq], st[mt][q]);
      }
    #pragma unroll
    for (int mt = 0; mt < 2; ++mt)
      #pragma unroll
      for (int q = 0; q < 2; ++q) {
        int dk = 16 * (2 * wid + q) + lo;
        #pragma unroll
        for (int r = 0; r < 4; ++r) {
          int dvr = 16 * mt + 4 * hi + r;
          STb[dvr][(((dk >> 3) ^ (dvr & 7)) << 3) | (dk & 7)] = (__bf16)st[mt][q][r];
        }
      }
    __syncthreads();
  }
}

// ---------------- launch ----------------
extern "C" void kernel_launch(void* const* d_in, const int* in_sizes, int n_in,
                              void* d_out, int out_size, void* d_ws, size_t ws_size,
                              hipStream_t stream) {
  (void)in_sizes; (void)n_in; (void)out_size; (void)ws_size;
  const float* hs   = (const float*)d_in[0];
  const float* cosT = (const float*)d_in[1];
  const float* sinT = (const float*)d_in[2];
  const float* Wq   = (const float*)d_in[3];
  const float* Wk   = (const float*)d_in[4];
  const float* Wv   = (const float*)d_in[5];
  const float* Wo   = (const float*)d_in[6];
  const float* fmq  = (const float*)d_in[7];
  const float* fmk  = (const float*)d_in[8];
  float* out = (float*)d_out;
  char* ws = (char*)d_ws;

  hipFuncSetAttribute((const void*)gemm256_kernel<float, 0>,
                      hipFuncAttributeMaxDynamicSharedMemorySize, 131072);
  hipFuncSetAttribute((const void*)gemm256_kernel<__bf16, 1>,
                      hipFuncAttributeMaxDynamicSharedMemorySize, 131072);
  hipFuncSetAttribute((const void*)gemm256_kernel<__bf16, 2>,
                      hipFuncAttributeMaxDynamicSharedMemorySize, 131072);

  // workspace map (MB offsets):
  //   0..59    Xb (bf16 hidden)          | later: qfb (0..34), kfb (34..68)
  //   70..98   Wqt                       | later: ob (70..137, over Wqt/Wkt/Wvt)
  //   104..119 Wkt
  //   119..134 Wvt
  //   140..169 Wot (live until O-GEMM)
  //   170..237 ropq  (written by Q-GEMM epilogue, rope layout (b,16,s,256))
  //   238..272 ropk  (written by K-GEMM epilogue, rope layout (b,8,s,256))
  //   272..306 vpb   (written by V-GEMM epilogue, (b,8,s,256))
  const size_t MB = 1024ull * 1024ull;
  __bf16* Xb   = (__bf16*)(ws + 0);
  __bf16* qfb  = (__bf16*)(ws + 0);
  __bf16* kfb  = (__bf16*)(ws + 34 * MB);
  __bf16* Wqt  = (__bf16*)(ws + 70 * MB);
  __bf16* ob   = (__bf16*)(ws + 70 * MB);
  __bf16* Wkt  = (__bf16*)(ws + 104 * MB);
  __bf16* Wvt  = (__bf16*)(ws + 119 * MB);
  __bf16* Wot  = (__bf16*)(ws + 140 * MB);
  __bf16* ropq = (__bf16*)(ws + 170 * MB);
  __bf16* ropk = (__bf16*)(ws + 238 * MB);
  __bf16* vpb  = (__bf16*)(ws + 272 * MB);

  convert_kernel<<<28672, 256, 0, stream>>>(hs, Xb, (size_t)8192 * 3584 / 4);
  transpose_kernel<<<dim3(128, 112), 256, 0, stream>>>(Wq, Wqt, 3584, 4096);
  transpose_kernel<<<dim3(64, 112),  256, 0, stream>>>(Wk, Wkt, 3584, 2048);
  transpose_kernel<<<dim3(64, 112),  256, 0, stream>>>(Wv, Wvt, 3584, 2048);
  transpose_kernel<<<dim3(112, 128), 256, 0, stream>>>(Wo, Wot, 4096, 3584);

  gemm256_kernel<__bf16, 1><<<dim3(16, 32), 512, 131072, stream>>>(
      Xb, Wqt, ropq, 8192, 4096, 3584, cosT, sinT, 16);
  gemm256_kernel<__bf16, 1><<<dim3(8, 32),  512, 131072, stream>>>(
      Xb, Wkt, ropk, 8192, 2048, 3584, cosT, sinT, 8);
  gemm256_kernel<__bf16, 2><<<dim3(8, 32),  512, 131072, stream>>>(
      Xb, Wvt, vpb, 8192, 2048, 3584, nullptr, nullptr, 8);

  fm_kernel<<<dim3(32, 32), 256, 0, stream>>>(ropq, fmq, qfb, 16, 0.08838834764831845f);
  fm_kernel<<<dim3(32, 32), 256, 0, stream>>>(ropk, fmk, kfb, 8, 1.0f);

  attn_kernel<<<256, 256, 0, stream>>>(qfb, kfb, vpb, ob);

  gemm256_kernel<float, 0><<<dim3(14, 32), 512, 131072, stream>>>(
      ob, Wot, out, 8192, 3584, 4096, nullptr, nullptr, 0);
}